// Round 4
// baseline (756.253 us; speedup 1.0000x reference)
//
#include <hip/hip_runtime.h>

#define S 2048
#define DM 512
#define NH 8
#define HD 64
#define NB 2
#define BH (NB * NH)
#define MROWS (NB * S) // 4096
#define QW (S / 32)    // 64 mask words per row

typedef __bf16 bf16x8 __attribute__((ext_vector_type(8)));
typedef float f32x4 __attribute__((ext_vector_type(4)));
typedef float nf4 __attribute__((ext_vector_type(4)));  // native vec for nontemporal
typedef int ni4 __attribute__((ext_vector_type(4)));    // native vec for nontemporal

// 0.125 (1/sqrt(HD)) * log2(e): folded into bf16 Q at projection time so the
// softmax exp becomes a bare v_exp_f32 (exp2) in both S*S passes.
#define QSCALE 0.18033688011112042f

// hardware 2^x (v_exp_f32) — same instruction __expf lowers to after its
// *log2e mul; avoids the glibc __exp2f macro collision.
__device__ __forceinline__ float hw_exp2(float x) {
  return __builtin_amdgcn_exp2f(x);
}

union FragU {
  uint4 u;
  bf16x8 v;
  unsigned short s[8];
};

__device__ __forceinline__ unsigned short f2bf(float x) {
  unsigned u = __float_as_uint(x);
  u += 0x7FFFu + ((u >> 16) & 1u); // RNE
  return (unsigned short)(u >> 16);
}

// ---------------- prep: wtrans + fp32->bf16 cvt + maskpack + Z zero ----------
// grid.x = 256 (wtrans) + 3072 (cvt) + 1024 (maskpack) + 32 (Zs zero) = 4384
__global__ __launch_bounds__(256) void k_prep(
    const float* __restrict__ w0, const float* __restrict__ w1,
    const float* __restrict__ w2, const float* __restrict__ w3,
    unsigned short* __restrict__ wt,
    const float* __restrict__ q, const float* __restrict__ k, const float* __restrict__ v,
    unsigned short* __restrict__ oq, unsigned short* __restrict__ ok, unsigned short* __restrict__ ov,
    const int* __restrict__ mask, unsigned* __restrict__ mp,
    float* __restrict__ Zs) {
  __shared__ float tile[64][65];
  int bid = blockIdx.x;
  int tid = threadIdx.x;
  if (bid < 256) {
    // ---- weight transpose + bf16: wt[i][n][k] = W_i[k][n]
    int i = bid >> 6, rem = bid & 63;
    const float* w = (i == 0) ? w0 : (i == 1) ? w1 : (i == 2) ? w2 : w3;
    int k0 = (rem & 7) * 64, n0 = (rem >> 3) * 64;
    int tx = tid & 63, ty = tid >> 6;
    for (int r = ty; r < 64; r += 4)
      tile[r][tx] = w[(size_t)(k0 + r) * DM + n0 + tx];
    __syncthreads();
    unsigned short* o = wt + (size_t)i * DM * DM;
    for (int r = ty; r < 64; r += 4)
      o[(size_t)(n0 + r) * DM + k0 + tx] = f2bf(tile[tx][r]);
  } else if (bid < 3328) {
    // ---- activation convert (read-once: nontemporal loads, protect L2)
    int b2 = bid - 256;
    int which = b2 >> 10;
    const float* src = (which == 0) ? q : (which == 1) ? k : v;
    unsigned short* dst = (which == 0) ? oq : (which == 1) ? ok : ov;
    size_t t = (size_t)(b2 & 1023) * 256 + tid;
    const nf4* s4 = (const nf4*)src + t * 2;
    nf4 x = __builtin_nontemporal_load(s4);
    nf4 y = __builtin_nontemporal_load(s4 + 1);
    FragU f;
    f.s[0] = f2bf(x.x); f.s[1] = f2bf(x.y); f.s[2] = f2bf(x.z); f.s[3] = f2bf(x.w);
    f.s[4] = f2bf(y.x); f.s[5] = f2bf(y.y); f.s[6] = f2bf(y.z); f.s[7] = f2bf(y.w);
    *(uint4*)(dst + t * 8) = f.u;
  } else if (bid < 4352) {
    // ---- mask bitpack: mp word t covers mask[t*32 .. t*32+31] (read-once: nt)
    size_t t = (size_t)(bid - 3328) * 256 + tid;
    const ni4* mb = (const ni4*)(mask + t * 32);
    unsigned bits = 0;
#pragma unroll
    for (int c = 0; c < 8; c++) {
      ni4 m = __builtin_nontemporal_load(mb + c);
      bits |= (m.x != 0 ? 1u : 0u) << (c * 4);
      bits |= (m.y != 0 ? 1u : 0u) << (c * 4 + 1);
      bits |= (m.z != 0 ? 1u : 0u) << (c * 4 + 2);
      bits |= (m.w != 0 ? 1u : 0u) << (c * 4 + 3);
    }
    mp[t] = bits;
  } else {
    // ---- zero Z accumulators (32768 floats)
    int t = (bid - 4352) * 256 + tid;
    ((float4*)Zs)[t] = make_float4(0.f, 0.f, 0.f, 0.f);
  }
}

// ---------------- QKV projection (V fused transpose -> vvT[bh][d][s]) -------
// Q output is pre-scaled by QSCALE so logits arrive in log2-domain units.
__global__ __launch_bounds__(256) void k_proj(
    const unsigned short* __restrict__ inq, const unsigned short* __restrict__ ink,
    const unsigned short* __restrict__ inv, const unsigned short* __restrict__ wt,
    const float* __restrict__ bq, const float* __restrict__ bk, const float* __restrict__ bv,
    unsigned short* __restrict__ oq, unsigned short* __restrict__ ok,
    unsigned short* __restrict__ vvT) {
  __shared__ __align__(16) unsigned short vt[64][72]; // [d][s_local]
  int which = blockIdx.z;
  const unsigned short* in = (which == 0) ? inq : (which == 1) ? ink : inv;
  const float* bias = (which == 0) ? bq : (which == 1) ? bk : bv;
  const unsigned short* w = wt + (size_t)which * DM * DM;

  int lane = threadIdx.x & 63, wv = threadIdx.x >> 6;
  int m0 = blockIdx.x * 64 + wv * 16;
  int n0 = blockIdx.y * 64;
  int kf = (lane >> 4) * 8;
  int arow = m0 + (lane & 15);

  f32x4 acc[4] = {{0.f, 0.f, 0.f, 0.f}, {0.f, 0.f, 0.f, 0.f},
                  {0.f, 0.f, 0.f, 0.f}, {0.f, 0.f, 0.f, 0.f}};

  for (int kk0 = 0; kk0 < DM; kk0 += 32) {
    FragU af;
    af.u = *(const uint4*)(in + (size_t)arow * DM + kk0 + kf);
#pragma unroll
    for (int nt = 0; nt < 4; nt++) {
      FragU bfr;
      bfr.u = *(const uint4*)(w + (size_t)(n0 + nt * 16 + (lane & 15)) * DM + kk0 + kf);
      acc[nt] = __builtin_amdgcn_mfma_f32_16x16x32_bf16(af.v, bfr.v, acc[nt], 0, 0, 0);
    }
  }

  if (which < 2) {
    unsigned short* out = (which == 0) ? oq : ok;
    float sc = (which == 0) ? QSCALE : 1.0f;
#pragma unroll
    for (int nt = 0; nt < 4; nt++) {
#pragma unroll
      for (int r = 0; r < 4; r++) {
        int row = m0 + (lane >> 4) * 4 + r;   // b*S + s
        int col = n0 + nt * 16 + (lane & 15); // h*64 + d
        float val = (acc[nt][r] + bias[col]) * sc;
        int b = row >> 11, sIdx = row & (S - 1);
        int h = col >> 6, d = col & 63;
        out[(((size_t)(b * NH + h) * S) + sIdx) * HD + d] = f2bf(val);
      }
    }
  } else {
    // stage bias-added bf16 tile transposed in LDS, then write vvT coalesced
#pragma unroll
    for (int nt = 0; nt < 4; nt++) {
#pragma unroll
      for (int r = 0; r < 4; r++) {
        int sl = wv * 16 + (lane >> 4) * 4 + r;
        int dl = nt * 16 + (lane & 15);
        vt[dl][sl] = f2bf(acc[nt][r] + bias[n0 + dl]);
      }
    }
    __syncthreads();
    int b = (blockIdx.x * 64) >> 11;
    int s0l = (blockIdx.x * 64) & (S - 1);
    int h = n0 >> 6;
    unsigned short* op = vvT + (size_t)(b * NH + h) * HD * S;
    int d = threadIdx.x >> 2;
    int sc2 = (threadIdx.x & 3) * 16;
#pragma unroll
    for (int j = 0; j < 2; j++)
      *(uint4*)&op[(size_t)d * S + s0l + sc2 + j * 8] = *(uint4*)&vt[d][sc2 + j * 8];
  }
}

// ---------------- pass 1: Zsum[bh][k] += sum_q exp(logit) (masked -> 0) ------
// Each wave owns TWO 16-row k-subtiles (k0 and k0+64): every Q/mask
// fragment load feeds two MFMA chains -> Q L2 traffic halved.
__global__ __launch_bounds__(256, 4) void k_softmax_z(
    const unsigned short* __restrict__ qq, const unsigned short* __restrict__ kk,
    const unsigned* __restrict__ mp, float* __restrict__ Zsum) {
  int lane = threadIdx.x & 63, w = threadIdx.x >> 6;
  int bh = blockIdx.y;
  int b = bh >> 3;
  int k0 = blockIdx.x * 128 + w * 16; // second subtile at k0 + 64
  int kf = (lane >> 4) * 8;
  int qbase = blockIdx.z * (S / 4);
  int krow_b = k0 + (lane >> 4) * 4;

  const unsigned short* kbase = kk + ((size_t)bh * S + k0 + (lane & 15)) * HD + kf;
  FragU a0, a1, a2, a3;
  a0.u = *(const uint4*)kbase;
  a1.u = *(const uint4*)(kbase + 32);
  a2.u = *(const uint4*)(kbase + 64 * HD);
  a3.u = *(const uint4*)(kbase + 64 * HD + 32);

  const unsigned short* qbaseP = qq + (size_t)bh * S * HD;
  const unsigned* mpb = mp + (size_t)b * S * QW;

  float sum0[4] = {0.f, 0.f, 0.f, 0.f};
  float sum1[4] = {0.f, 0.f, 0.f, 0.f};

  for (int q0 = qbase; q0 < qbase + S / 4; q0 += 64) {
    uint2 mw0[4], mw1[4];
#pragma unroll
    for (int r = 0; r < 4; r++) {
      mw0[r] = *(const uint2*)&mpb[(size_t)(krow_b + r) * QW + (q0 >> 5)];
      mw1[r] = *(const uint2*)&mpb[(size_t)(krow_b + 64 + r) * QW + (q0 >> 5)];
    }
#pragma unroll
    for (int nt = 0; nt < 4; nt++) {
      int qcol = q0 + nt * 16 + (lane & 15);
      const unsigned short* qp = qbaseP + (size_t)qcol * HD + kf;
      FragU b0, b1;
      b0.u = *(const uint4*)qp;
      b1.u = *(const uint4*)(qp + 32);
      f32x4 c0 = {0.f, 0.f, 0.f, 0.f};
      f32x4 c1 = {0.f, 0.f, 0.f, 0.f};
      c0 = __builtin_amdgcn_mfma_f32_16x16x32_bf16(a0.v, b0.v, c0, 0, 0, 0);
      c0 = __builtin_amdgcn_mfma_f32_16x16x32_bf16(a1.v, b1.v, c0, 0, 0, 0);
      c1 = __builtin_amdgcn_mfma_f32_16x16x32_bf16(a2.v, b0.v, c1, 0, 0, 0);
      c1 = __builtin_amdgcn_mfma_f32_16x16x32_bf16(a3.v, b1.v, c1, 0, 0, 0);
      unsigned bpos = (unsigned)(nt * 16 + (lane & 15)) & 31u;
#pragma unroll
      for (int r = 0; r < 4; r++) {
        unsigned wd0 = (nt < 2) ? mw0[r].x : mw0[r].y;
        unsigned wd1 = (nt < 2) ? mw1[r].x : mw1[r].y;
        float e0 = hw_exp2(c0[r]);
        float e1 = hw_exp2(c1[r]);
        sum0[r] += ((wd0 >> bpos) & 1u) ? 0.f : e0;
        sum1[r] += ((wd1 >> bpos) & 1u) ? 0.f : e1;
      }
    }
  }
#pragma unroll
  for (int r = 0; r < 4; r++) {
    float s = sum0[r];
    s += __shfl_xor(s, 1);
    s += __shfl_xor(s, 2);
    s += __shfl_xor(s, 4);
    s += __shfl_xor(s, 8);
    if ((lane & 15) == 0)
      atomicAdd(&Zsum[(size_t)bh * S + krow_b + r], s);
    float t = sum1[r];
    t += __shfl_xor(t, 1);
    t += __shfl_xor(t, 2);
    t += __shfl_xor(t, 4);
    t += __shfl_xor(t, 8);
    if ((lane & 15) == 0)
      atomicAdd(&Zsum[(size_t)bh * S + krow_b + 64 + r], t);
  }
}

// ---------------- pass 2: attn write + O = A^T V (both k-halves in-block) ----
// 8 waves: group g = w>>2 owns k-half g. Partial O reduced through LDS,
// written directly as bf16 concat — no pO round-trip, no k_reduceO.
__global__ __launch_bounds__(512, 4) void k_attn(
    const unsigned short* __restrict__ qq, const unsigned short* __restrict__ kk,
    const unsigned short* __restrict__ vvT, const unsigned* __restrict__ mp,
    const float* __restrict__ Zsum, float* __restrict__ attn_out,
    unsigned short* __restrict__ conc) {
  __shared__ __align__(16) unsigned short pT[2][2][64][72]; // [group][buf][q_local][k_local]
  int lane = threadIdx.x & 63, w = threadIdx.x >> 6;
  int g = w >> 2, w4 = w & 3;
  int bh = blockIdx.y;
  int b = bh >> 3, h = bh & 7;
  int q0 = blockIdx.x * 64;
  int kf = (lane >> 4) * 8;

  // resident Q B-frags (reused for every k-tile)
  FragU bq[4][2];
#pragma unroll
  for (int nt = 0; nt < 4; nt++) {
    const unsigned short* qp = qq + ((size_t)bh * S + q0 + nt * 16 + (lane & 15)) * HD + kf;
    bq[nt][0].u = *(const uint4*)qp;
    bq[nt][1].u = *(const uint4*)(qp + 32);
  }

  f32x4 o[4] = {{0.f, 0.f, 0.f, 0.f}, {0.f, 0.f, 0.f, 0.f},
                {0.f, 0.f, 0.f, 0.f}, {0.f, 0.f, 0.f, 0.f}};

  const unsigned short* kkb = kk + (size_t)bh * S * HD;
  const unsigned short* vb = vvT + (size_t)bh * HD * S;
  const unsigned* mpb = mp + (size_t)b * S * QW;
  float* ao = attn_out + (size_t)bh * S * S;
  const float* zb = Zsum + (size_t)bh * S;
  int q0w = q0 >> 5;
  int kbase = g * (S / 2);

  int buf = 0;
  for (int k0 = kbase; k0 < kbase + S / 2; k0 += 64) {
    int kw = k0 + w4 * 16;
    int krow_b = kw + (lane >> 4) * 4;
    const unsigned short* kp = kkb + (size_t)(kw + (lane & 15)) * HD + kf;
    FragU a0, a1;
    a0.u = *(const uint4*)kp;
    a1.u = *(const uint4*)(kp + 32);
    float iz[4];
    uint2 mw[4];
#pragma unroll
    for (int r = 0; r < 4; r++) {
      iz[r] = 1.0f / zb[krow_b + r];
      mw[r] = *(const uint2*)&mpb[(size_t)(krow_b + r) * QW + q0w];
    }

#pragma unroll
    for (int nt = 0; nt < 4; nt++) {
      f32x4 c = {0.f, 0.f, 0.f, 0.f};
      c = __builtin_amdgcn_mfma_f32_16x16x32_bf16(a0.v, bq[nt][0].v, c, 0, 0, 0);
      c = __builtin_amdgcn_mfma_f32_16x16x32_bf16(a1.v, bq[nt][1].v, c, 0, 0, 0);
      int ql = nt * 16 + (lane & 15);
      int qcol = q0 + ql;
      unsigned bpos = (unsigned)ql & 31u;
#pragma unroll
      for (int r = 0; r < 4; r++) {
        int kl = w4 * 16 + (lane >> 4) * 4 + r;
        int krow = k0 + kl;
        unsigned word = (nt < 2) ? mw[r].x : mw[r].y;
        float a = ((word >> bpos) & 1u) ? 0.f : hw_exp2(c[r]) * iz[r];
        // attn is write-once, never re-read: keep it out of L2 so K/V stay hot
        __builtin_nontemporal_store(a, &ao[(size_t)krow * S + qcol]);
        pT[g][buf][ql][kl] = f2bf(a);
      }
    }
    __syncthreads();
    // waves' own lgkmcnt(0) drains before their next barrier, so reading buf here
    // is safe against the write to the same buf two iterations later.
#pragma unroll
    for (int ks = 0; ks < 2; ks++) {
      FragU af;
      af.u = *(const uint4*)(&pT[g][buf][w4 * 16 + (lane & 15)][kf + ks * 32]);
#pragma unroll
      for (int nt = 0; nt < 4; nt++) {
        FragU bfr;
        bfr.u = *(const uint4*)(vb + (size_t)(nt * 16 + (lane & 15)) * S + k0 + kf + ks * 32);
        o[nt] = __builtin_amdgcn_mfma_f32_16x16x32_bf16(af.v, bfr.v, o[nt], 0, 0, 0);
      }
    }
    buf ^= 1;
  }

  // ---- cross-group O reduction through LDS (aliased over pT), write conc ----
  __syncthreads(); // all PV reads of pT done before we clobber it
  float* oacc = (float*)&pT[0][0][0][0]; // 64 rows x 65 floats = 16.6 KB
  int qr = w4 * 16 + (lane >> 4) * 4;
  if (g == 1) {
#pragma unroll
    for (int nt = 0; nt < 4; nt++)
#pragma unroll
      for (int r = 0; r < 4; r++)
        oacc[(qr + r) * 65 + nt * 16 + (lane & 15)] = o[nt][r];
  }
  __syncthreads();
  if (g == 0) {
#pragma unroll
    for (int nt = 0; nt < 4; nt++) {
#pragma unroll
      for (int r = 0; r < 4; r++) {
        int qg = q0 + qr + r;
        int col = h * 64 + nt * 16 + (lane & 15);
        float s = o[nt][r] + oacc[(qr + r) * 65 + nt * 16 + (lane & 15)];
        conc[((size_t)(b * S + qg)) * DM + col] = f2bf(s);
      }
    }
  }
}

// ---------------- out projection: out = concat @ Wo + bo ---------------------
__global__ __launch_bounds__(256) void k_outproj(
    const unsigned short* __restrict__ concat, const unsigned short* __restrict__ wt,
    const float* __restrict__ bias, float* __restrict__ out) {
  const unsigned short* w = wt + (size_t)3 * DM * DM;
  int lane = threadIdx.x & 63, wv = threadIdx.x >> 6;
  int m0 = blockIdx.x * 64 + wv * 16;
  int n0 = blockIdx.y * 64;
  int kf = (lane >> 4) * 8;

  f32x4 acc[4] = {{0.f, 0.f, 0.f, 0.f}, {0.f, 0.f, 0.f, 0.f},
                  {0.f, 0.f, 0.f, 0.f}, {0.f, 0.f, 0.f, 0.f}};

  for (int kk0 = 0; kk0 < DM; kk0 += 32) {
    FragU af;
    af.u = *(const uint4*)(concat + (size_t)(m0 + (lane & 15)) * DM + kk0 + kf);
#pragma unroll
    for (int nt = 0; nt < 4; nt++) {
      FragU bfr;
      bfr.u = *(const uint4*)(w + (size_t)(n0 + nt * 16 + (lane & 15)) * DM + kk0 + kf);
      acc[nt] = __builtin_amdgcn_mfma_f32_16x16x32_bf16(af.v, bfr.v, acc[nt], 0, 0, 0);
    }
  }
#pragma unroll
  for (int nt = 0; nt < 4; nt++) {
#pragma unroll
    for (int r = 0; r < 4; r++) {
      int row = m0 + (lane >> 4) * 4 + r;
      int col = n0 + nt * 16 + (lane & 15);
      out[(size_t)row * DM + col] = acc[nt][r] + bias[col];
    }
  }
}

extern "C" void kernel_launch(void* const* d_in, const int* in_sizes, int n_in,
                              void* d_out, int out_size, void* d_ws, size_t ws_size,
                              hipStream_t stream) {
  (void)in_sizes; (void)n_in; (void)out_size; (void)ws_size;
  const float* v    = (const float*)d_in[0];
  const float* q    = (const float*)d_in[1];
  const float* k    = (const float*)d_in[2];
  const int*   mask = (const int*)d_in[3];
  const float* wq_w = (const float*)d_in[4];
  const float* wq_b = (const float*)d_in[5];
  const float* wk_w = (const float*)d_in[6];
  const float* wk_b = (const float*)d_in[7];
  const float* wv_w = (const float*)d_in[8];
  const float* wv_b = (const float*)d_in[9];
  const float* wo_w = (const float*)d_in[10];
  const float* wo_b = (const float*)d_in[11];

  char* ws = (char*)d_ws;
  size_t off = 0;
  auto alloc = [&](size_t bytes) {
    char* p = ws + off;
    off += (bytes + 255) & ~(size_t)255;
    return p;
  };
  unsigned short* wt   = (unsigned short*)alloc((size_t)4 * DM * DM * 2);   // 2 MB
  unsigned short* qbf  = (unsigned short*)alloc((size_t)MROWS * DM * 2);    // 4 MB
  unsigned short* kbf  = (unsigned short*)alloc((size_t)MROWS * DM * 2);    // 4 MB
  unsigned short* vbf  = (unsigned short*)alloc((size_t)MROWS * DM * 2);    // 4 MB
  unsigned short* qq   = (unsigned short*)alloc((size_t)BH * S * HD * 2);   // 4 MB
  unsigned short* kk2  = (unsigned short*)alloc((size_t)BH * S * HD * 2);   // 4 MB
  unsigned short* vvT  = (unsigned short*)alloc((size_t)BH * S * HD * 2);   // 4 MB
  unsigned*       mp   = (unsigned*)alloc((size_t)NB * S * QW * 4);         // 1 MB
  float*          Zs   = (float*)alloc((size_t)BH * S * 4);                 // 128 KB
  unsigned short* conc = (unsigned short*)alloc((size_t)MROWS * DM * 2);    // 4 MB

  float* out_final = (float*)d_out;
  float* out_attn  = (float*)d_out + (size_t)MROWS * DM;

  k_prep<<<dim3(4384), 256, 0, stream>>>(wq_w, wk_w, wv_w, wo_w, wt,
                                          q, k, v, qbf, kbf, vbf,
                                          mask, mp, Zs);
  k_proj<<<dim3(64, 8, 3), 256, 0, stream>>>(qbf, kbf, vbf, wt, wq_b, wk_b, wv_b,
                                              qq, kk2, vvT);
  k_softmax_z<<<dim3(16, 16, 4), 256, 0, stream>>>(qq, kk2, mp, Zs);
  k_attn<<<dim3(32, 16), 512, 0, stream>>>(qq, kk2, vvT, mp, Zs, out_attn, conc);
  k_outproj<<<dim3(64, 8), 256, 0, stream>>>(conc, wt, wo_b, out_final);
}

// Round 5
// 537.906 us; speedup vs baseline: 1.4059x; 1.4059x over previous
//
#include <hip/hip_runtime.h>

#define S 2048
#define DM 512
#define NH 8
#define HD 64
#define NB 2
#define BH (NB * NH)
#define MROWS (NB * S) // 4096
#define QW (S / 32)    // 64 mask words per row

typedef __bf16 bf16x8 __attribute__((ext_vector_type(8)));
typedef float f32x4 __attribute__((ext_vector_type(4)));
typedef float nf4 __attribute__((ext_vector_type(4)));  // native vec for nontemporal
typedef int ni4 __attribute__((ext_vector_type(4)));    // native vec for nontemporal

// 0.125 (1/sqrt(HD)) * log2(e): folded into bf16 Q at projection time so the
// softmax exp becomes a bare v_exp_f32 (exp2) in both S*S passes.
#define QSCALE 0.18033688011112042f

// hardware 2^x (v_exp_f32) — same instruction __expf lowers to after its
// *log2e mul; avoids the glibc __exp2f macro collision.
__device__ __forceinline__ float hw_exp2(float x) {
  return __builtin_amdgcn_exp2f(x);
}

union FragU {
  uint4 u;
  bf16x8 v;
  unsigned short s[8];
};

__device__ __forceinline__ unsigned short f2bf(float x) {
  unsigned u = __float_as_uint(x);
  u += 0x7FFFu + ((u >> 16) & 1u); // RNE
  return (unsigned short)(u >> 16);
}

// ---------------- prep: wtrans + fp32->bf16 cvt + maskpack + Z zero ----------
// grid.x = 256 (wtrans) + 3072 (cvt) + 1024 (maskpack) + 32 (Zs zero) = 4384
__global__ __launch_bounds__(256) void k_prep(
    const float* __restrict__ w0, const float* __restrict__ w1,
    const float* __restrict__ w2, const float* __restrict__ w3,
    unsigned short* __restrict__ wt,
    const float* __restrict__ q, const float* __restrict__ k, const float* __restrict__ v,
    unsigned short* __restrict__ oq, unsigned short* __restrict__ ok, unsigned short* __restrict__ ov,
    const int* __restrict__ mask, unsigned* __restrict__ mp,
    float* __restrict__ Zs) {
  __shared__ float tile[64][65];
  int bid = blockIdx.x;
  int tid = threadIdx.x;
  if (bid < 256) {
    // ---- weight transpose + bf16: wt[i][n][k] = W_i[k][n]
    int i = bid >> 6, rem = bid & 63;
    const float* w = (i == 0) ? w0 : (i == 1) ? w1 : (i == 2) ? w2 : w3;
    int k0 = (rem & 7) * 64, n0 = (rem >> 3) * 64;
    int tx = tid & 63, ty = tid >> 6;
    for (int r = ty; r < 64; r += 4)
      tile[r][tx] = w[(size_t)(k0 + r) * DM + n0 + tx];
    __syncthreads();
    unsigned short* o = wt + (size_t)i * DM * DM;
    for (int r = ty; r < 64; r += 4)
      o[(size_t)(n0 + r) * DM + k0 + tx] = f2bf(tile[tx][r]);
  } else if (bid < 3328) {
    // ---- activation convert (read-once: nontemporal loads, protect L2)
    int b2 = bid - 256;
    int which = b2 >> 10;
    const float* src = (which == 0) ? q : (which == 1) ? k : v;
    unsigned short* dst = (which == 0) ? oq : (which == 1) ? ok : ov;
    size_t t = (size_t)(b2 & 1023) * 256 + tid;
    const nf4* s4 = (const nf4*)src + t * 2;
    nf4 x = __builtin_nontemporal_load(s4);
    nf4 y = __builtin_nontemporal_load(s4 + 1);
    FragU f;
    f.s[0] = f2bf(x.x); f.s[1] = f2bf(x.y); f.s[2] = f2bf(x.z); f.s[3] = f2bf(x.w);
    f.s[4] = f2bf(y.x); f.s[5] = f2bf(y.y); f.s[6] = f2bf(y.z); f.s[7] = f2bf(y.w);
    *(uint4*)(dst + t * 8) = f.u;
  } else if (bid < 4352) {
    // ---- mask bitpack: mp word t covers mask[t*32 .. t*32+31] (read-once: nt)
    size_t t = (size_t)(bid - 3328) * 256 + tid;
    const ni4* mb = (const ni4*)(mask + t * 32);
    unsigned bits = 0;
#pragma unroll
    for (int c = 0; c < 8; c++) {
      ni4 m = __builtin_nontemporal_load(mb + c);
      bits |= (m.x != 0 ? 1u : 0u) << (c * 4);
      bits |= (m.y != 0 ? 1u : 0u) << (c * 4 + 1);
      bits |= (m.z != 0 ? 1u : 0u) << (c * 4 + 2);
      bits |= (m.w != 0 ? 1u : 0u) << (c * 4 + 3);
    }
    mp[t] = bits;
  } else {
    // ---- zero Z accumulators (32768 floats)
    int t = (bid - 4352) * 256 + tid;
    ((float4*)Zs)[t] = make_float4(0.f, 0.f, 0.f, 0.f);
  }
}

// ---------------- QKV projection (V fused transpose -> vvT[bh][d][s]) -------
// Q output is pre-scaled by QSCALE so logits arrive in log2-domain units.
__global__ __launch_bounds__(256) void k_proj(
    const unsigned short* __restrict__ inq, const unsigned short* __restrict__ ink,
    const unsigned short* __restrict__ inv, const unsigned short* __restrict__ wt,
    const float* __restrict__ bq, const float* __restrict__ bk, const float* __restrict__ bv,
    unsigned short* __restrict__ oq, unsigned short* __restrict__ ok,
    unsigned short* __restrict__ vvT) {
  __shared__ __align__(16) unsigned short vt[64][72]; // [d][s_local]
  int which = blockIdx.z;
  const unsigned short* in = (which == 0) ? inq : (which == 1) ? ink : inv;
  const float* bias = (which == 0) ? bq : (which == 1) ? bk : bv;
  const unsigned short* w = wt + (size_t)which * DM * DM;

  int lane = threadIdx.x & 63, wv = threadIdx.x >> 6;
  int m0 = blockIdx.x * 64 + wv * 16;
  int n0 = blockIdx.y * 64;
  int kf = (lane >> 4) * 8;
  int arow = m0 + (lane & 15);

  f32x4 acc[4] = {{0.f, 0.f, 0.f, 0.f}, {0.f, 0.f, 0.f, 0.f},
                  {0.f, 0.f, 0.f, 0.f}, {0.f, 0.f, 0.f, 0.f}};

  for (int kk0 = 0; kk0 < DM; kk0 += 32) {
    FragU af;
    af.u = *(const uint4*)(in + (size_t)arow * DM + kk0 + kf);
#pragma unroll
    for (int nt = 0; nt < 4; nt++) {
      FragU bfr;
      bfr.u = *(const uint4*)(w + (size_t)(n0 + nt * 16 + (lane & 15)) * DM + kk0 + kf);
      acc[nt] = __builtin_amdgcn_mfma_f32_16x16x32_bf16(af.v, bfr.v, acc[nt], 0, 0, 0);
    }
  }

  if (which < 2) {
    unsigned short* out = (which == 0) ? oq : ok;
    float sc = (which == 0) ? QSCALE : 1.0f;
#pragma unroll
    for (int nt = 0; nt < 4; nt++) {
#pragma unroll
      for (int r = 0; r < 4; r++) {
        int row = m0 + (lane >> 4) * 4 + r;   // b*S + s
        int col = n0 + nt * 16 + (lane & 15); // h*64 + d
        float val = (acc[nt][r] + bias[col]) * sc;
        int b = row >> 11, sIdx = row & (S - 1);
        int h = col >> 6, d = col & 63;
        out[(((size_t)(b * NH + h) * S) + sIdx) * HD + d] = f2bf(val);
      }
    }
  } else {
    // stage bias-added bf16 tile transposed in LDS, then write vvT coalesced
#pragma unroll
    for (int nt = 0; nt < 4; nt++) {
#pragma unroll
      for (int r = 0; r < 4; r++) {
        int sl = wv * 16 + (lane >> 4) * 4 + r;
        int dl = nt * 16 + (lane & 15);
        vt[dl][sl] = f2bf(acc[nt][r] + bias[n0 + dl]);
      }
    }
    __syncthreads();
    int b = (blockIdx.x * 64) >> 11;
    int s0l = (blockIdx.x * 64) & (S - 1);
    int h = n0 >> 6;
    unsigned short* op = vvT + (size_t)(b * NH + h) * HD * S;
    int d = threadIdx.x >> 2;
    int sc2 = (threadIdx.x & 3) * 16;
#pragma unroll
    for (int j = 0; j < 2; j++)
      *(uint4*)&op[(size_t)d * S + s0l + sc2 + j * 8] = *(uint4*)&vt[d][sc2 + j * 8];
  }
}

// ---------------- pass 1: Zsum[bh][k] += sum_q exp(logit) (masked -> 0) ------
// Round-2 structure (verified L2-resident): grid (32,16,2), one 16-row
// k-subtile per wave, q-half per block. Per-XCD working set ~1.5 MB < 4 MB L2.
__global__ __launch_bounds__(256, 4) void k_softmax_z(
    const unsigned short* __restrict__ qq, const unsigned short* __restrict__ kk,
    const unsigned* __restrict__ mp, float* __restrict__ Zsum) {
  int lane = threadIdx.x & 63, w = threadIdx.x >> 6;
  int bh = blockIdx.y;
  int b = bh >> 3;
  int k0 = blockIdx.x * 64 + w * 16;
  int kf = (lane >> 4) * 8;
  int qbase = blockIdx.z * (S / 2);
  int krow_b = k0 + (lane >> 4) * 4;

  const unsigned short* kbase = kk + ((size_t)bh * S + k0 + (lane & 15)) * HD + kf;
  FragU a0, a1;
  a0.u = *(const uint4*)kbase;
  a1.u = *(const uint4*)(kbase + 32);

  const unsigned short* qbaseP = qq + (size_t)bh * S * HD;
  const unsigned* mpb = mp + (size_t)b * S * QW;

  float sum[4] = {0.f, 0.f, 0.f, 0.f};

  for (int q0 = qbase; q0 < qbase + S / 2; q0 += 64) {
    uint2 mw[4];
#pragma unroll
    for (int r = 0; r < 4; r++)
      mw[r] = *(const uint2*)&mpb[(size_t)(krow_b + r) * QW + (q0 >> 5)];
#pragma unroll
    for (int nt = 0; nt < 4; nt++) {
      int qcol = q0 + nt * 16 + (lane & 15);
      const unsigned short* qp = qbaseP + (size_t)qcol * HD + kf;
      FragU b0, b1;
      b0.u = *(const uint4*)qp;
      b1.u = *(const uint4*)(qp + 32);
      f32x4 c = {0.f, 0.f, 0.f, 0.f};
      c = __builtin_amdgcn_mfma_f32_16x16x32_bf16(a0.v, b0.v, c, 0, 0, 0);
      c = __builtin_amdgcn_mfma_f32_16x16x32_bf16(a1.v, b1.v, c, 0, 0, 0);
      unsigned bpos = (unsigned)(nt * 16 + (lane & 15)) & 31u;
#pragma unroll
      for (int r = 0; r < 4; r++) {
        unsigned word = (nt < 2) ? mw[r].x : mw[r].y;
        float e = hw_exp2(c[r]);
        sum[r] += ((word >> bpos) & 1u) ? 0.f : e;
      }
    }
  }
#pragma unroll
  for (int r = 0; r < 4; r++) {
    float s = sum[r];
    s += __shfl_xor(s, 1);
    s += __shfl_xor(s, 2);
    s += __shfl_xor(s, 4);
    s += __shfl_xor(s, 8);
    if ((lane & 15) == 0)
      atomicAdd(&Zsum[(size_t)bh * S + krow_b + r], s);
  }
}

// ---------------- pass 2: attn write + O = A^T V (both k-halves in-block) ----
// 8 waves: group g = w>>2 owns k-half g. Partial O reduced through LDS,
// written directly as bf16 concat — no pO round-trip, no k_reduceO.
__global__ __launch_bounds__(512, 4) void k_attn(
    const unsigned short* __restrict__ qq, const unsigned short* __restrict__ kk,
    const unsigned short* __restrict__ vvT, const unsigned* __restrict__ mp,
    const float* __restrict__ Zsum, float* __restrict__ attn_out,
    unsigned short* __restrict__ conc) {
  __shared__ __align__(16) unsigned short pT[2][2][64][72]; // [group][buf][q_local][k_local]
  int lane = threadIdx.x & 63, w = threadIdx.x >> 6;
  int g = w >> 2, w4 = w & 3;
  int bh = blockIdx.y;
  int b = bh >> 3, h = bh & 7;
  int q0 = blockIdx.x * 64;
  int kf = (lane >> 4) * 8;

  // resident Q B-frags (reused for every k-tile)
  FragU bq[4][2];
#pragma unroll
  for (int nt = 0; nt < 4; nt++) {
    const unsigned short* qp = qq + ((size_t)bh * S + q0 + nt * 16 + (lane & 15)) * HD + kf;
    bq[nt][0].u = *(const uint4*)qp;
    bq[nt][1].u = *(const uint4*)(qp + 32);
  }

  f32x4 o[4] = {{0.f, 0.f, 0.f, 0.f}, {0.f, 0.f, 0.f, 0.f},
                {0.f, 0.f, 0.f, 0.f}, {0.f, 0.f, 0.f, 0.f}};

  const unsigned short* kkb = kk + (size_t)bh * S * HD;
  const unsigned short* vb = vvT + (size_t)bh * HD * S;
  const unsigned* mpb = mp + (size_t)b * S * QW;
  float* ao = attn_out + (size_t)bh * S * S;
  const float* zb = Zsum + (size_t)bh * S;
  int q0w = q0 >> 5;
  int kbase = g * (S / 2);

  int buf = 0;
  for (int k0 = kbase; k0 < kbase + S / 2; k0 += 64) {
    int kw = k0 + w4 * 16;
    int krow_b = kw + (lane >> 4) * 4;
    const unsigned short* kp = kkb + (size_t)(kw + (lane & 15)) * HD + kf;
    FragU a0, a1;
    a0.u = *(const uint4*)kp;
    a1.u = *(const uint4*)(kp + 32);
    float iz[4];
    uint2 mw[4];
#pragma unroll
    for (int r = 0; r < 4; r++) {
      iz[r] = 1.0f / zb[krow_b + r];
      mw[r] = *(const uint2*)&mpb[(size_t)(krow_b + r) * QW + q0w];
    }

#pragma unroll
    for (int nt = 0; nt < 4; nt++) {
      f32x4 c = {0.f, 0.f, 0.f, 0.f};
      c = __builtin_amdgcn_mfma_f32_16x16x32_bf16(a0.v, bq[nt][0].v, c, 0, 0, 0);
      c = __builtin_amdgcn_mfma_f32_16x16x32_bf16(a1.v, bq[nt][1].v, c, 0, 0, 0);
      int ql = nt * 16 + (lane & 15);
      int qcol = q0 + ql;
      unsigned bpos = (unsigned)ql & 31u;
#pragma unroll
      for (int r = 0; r < 4; r++) {
        int kl = w4 * 16 + (lane >> 4) * 4 + r;
        int krow = k0 + kl;
        unsigned word = (nt < 2) ? mw[r].x : mw[r].y;
        float a = ((word >> bpos) & 1u) ? 0.f : hw_exp2(c[r]) * iz[r];
        // attn is write-once, never re-read: keep it out of L2 so K/V stay hot
        __builtin_nontemporal_store(a, &ao[(size_t)krow * S + qcol]);
        pT[g][buf][ql][kl] = f2bf(a);
      }
    }
    __syncthreads();
    // waves' own lgkmcnt(0) drains before their next barrier, so reading buf here
    // is safe against the write to the same buf two iterations later.
#pragma unroll
    for (int ks = 0; ks < 2; ks++) {
      FragU af;
      af.u = *(const uint4*)(&pT[g][buf][w4 * 16 + (lane & 15)][kf + ks * 32]);
#pragma unroll
      for (int nt = 0; nt < 4; nt++) {
        FragU bfr;
        bfr.u = *(const uint4*)(vb + (size_t)(nt * 16 + (lane & 15)) * S + k0 + kf + ks * 32);
        o[nt] = __builtin_amdgcn_mfma_f32_16x16x32_bf16(af.v, bfr.v, o[nt], 0, 0, 0);
      }
    }
    buf ^= 1;
  }

  // ---- cross-group O reduction through LDS (aliased over pT), write conc ----
  __syncthreads(); // all PV reads of pT done before we clobber it
  float* oacc = (float*)&pT[0][0][0][0]; // 64 rows x 65 floats = 16.6 KB
  int qr = w4 * 16 + (lane >> 4) * 4;
  if (g == 1) {
#pragma unroll
    for (int nt = 0; nt < 4; nt++)
#pragma unroll
      for (int r = 0; r < 4; r++)
        oacc[(qr + r) * 65 + nt * 16 + (lane & 15)] = o[nt][r];
  }
  __syncthreads();
  if (g == 0) {
#pragma unroll
    for (int nt = 0; nt < 4; nt++) {
#pragma unroll
      for (int r = 0; r < 4; r++) {
        int qg = q0 + qr + r;
        int col = h * 64 + nt * 16 + (lane & 15);
        float s = o[nt][r] + oacc[(qr + r) * 65 + nt * 16 + (lane & 15)];
        conc[((size_t)(b * S + qg)) * DM + col] = f2bf(s);
      }
    }
  }
}

// ---------------- out projection: out = concat @ Wo + bo ---------------------
__global__ __launch_bounds__(256) void k_outproj(
    const unsigned short* __restrict__ concat, const unsigned short* __restrict__ wt,
    const float* __restrict__ bias, float* __restrict__ out) {
  const unsigned short* w = wt + (size_t)3 * DM * DM;
  int lane = threadIdx.x & 63, wv = threadIdx.x >> 6;
  int m0 = blockIdx.x * 64 + wv * 16;
  int n0 = blockIdx.y * 64;
  int kf = (lane >> 4) * 8;

  f32x4 acc[4] = {{0.f, 0.f, 0.f, 0.f}, {0.f, 0.f, 0.f, 0.f},
                  {0.f, 0.f, 0.f, 0.f}, {0.f, 0.f, 0.f, 0.f}};

  for (int kk0 = 0; kk0 < DM; kk0 += 32) {
    FragU af;
    af.u = *(const uint4*)(concat + (size_t)(m0 + (lane & 15)) * DM + kk0 + kf);
#pragma unroll
    for (int nt = 0; nt < 4; nt++) {
      FragU bfr;
      bfr.u = *(const uint4*)(w + (size_t)(n0 + nt * 16 + (lane & 15)) * DM + kk0 + kf);
      acc[nt] = __builtin_amdgcn_mfma_f32_16x16x32_bf16(af.v, bfr.v, acc[nt], 0, 0, 0);
    }
  }
#pragma unroll
  for (int nt = 0; nt < 4; nt++) {
#pragma unroll
    for (int r = 0; r < 4; r++) {
      int row = m0 + (lane >> 4) * 4 + r;
      int col = n0 + nt * 16 + (lane & 15);
      out[(size_t)row * DM + col] = acc[nt][r] + bias[col];
    }
  }
}

extern "C" void kernel_launch(void* const* d_in, const int* in_sizes, int n_in,
                              void* d_out, int out_size, void* d_ws, size_t ws_size,
                              hipStream_t stream) {
  (void)in_sizes; (void)n_in; (void)out_size; (void)ws_size;
  const float* v    = (const float*)d_in[0];
  const float* q    = (const float*)d_in[1];
  const float* k    = (const float*)d_in[2];
  const int*   mask = (const int*)d_in[3];
  const float* wq_w = (const float*)d_in[4];
  const float* wq_b = (const float*)d_in[5];
  const float* wk_w = (const float*)d_in[6];
  const float* wk_b = (const float*)d_in[7];
  const float* wv_w = (const float*)d_in[8];
  const float* wv_b = (const float*)d_in[9];
  const float* wo_w = (const float*)d_in[10];
  const float* wo_b = (const float*)d_in[11];

  char* ws = (char*)d_ws;
  size_t off = 0;
  auto alloc = [&](size_t bytes) {
    char* p = ws + off;
    off += (bytes + 255) & ~(size_t)255;
    return p;
  };
  unsigned short* wt   = (unsigned short*)alloc((size_t)4 * DM * DM * 2);   // 2 MB
  unsigned short* qbf  = (unsigned short*)alloc((size_t)MROWS * DM * 2);    // 4 MB
  unsigned short* kbf  = (unsigned short*)alloc((size_t)MROWS * DM * 2);    // 4 MB
  unsigned short* vbf  = (unsigned short*)alloc((size_t)MROWS * DM * 2);    // 4 MB
  unsigned short* qq   = (unsigned short*)alloc((size_t)BH * S * HD * 2);   // 4 MB
  unsigned short* kk2  = (unsigned short*)alloc((size_t)BH * S * HD * 2);   // 4 MB
  unsigned short* vvT  = (unsigned short*)alloc((size_t)BH * S * HD * 2);   // 4 MB
  unsigned*       mp   = (unsigned*)alloc((size_t)NB * S * QW * 4);         // 1 MB
  float*          Zs   = (float*)alloc((size_t)BH * S * 4);                 // 128 KB
  unsigned short* conc = (unsigned short*)alloc((size_t)MROWS * DM * 2);    // 4 MB

  float* out_final = (float*)d_out;
  float* out_attn  = (float*)d_out + (size_t)MROWS * DM;

  k_prep<<<dim3(4384), 256, 0, stream>>>(wq_w, wk_w, wv_w, wo_w, wt,
                                          q, k, v, qbf, kbf, vbf,
                                          mask, mp, Zs);
  k_proj<<<dim3(64, 8, 3), 256, 0, stream>>>(qbf, kbf, vbf, wt, wq_b, wk_b, wv_b,
                                              qq, kk2, vvT);
  k_softmax_z<<<dim3(32, 16, 2), 256, 0, stream>>>(qq, kk2, mp, Zs);
  k_attn<<<dim3(32, 16), 512, 0, stream>>>(qq, kk2, vvT, mp, Zs, out_attn, conc);
  k_outproj<<<dim3(64, 8), 256, 0, stream>>>(conc, wt, wo_b, out_final);
}

// Round 6
// 492.157 us; speedup vs baseline: 1.5366x; 1.0930x over previous
//
#include <hip/hip_runtime.h>

#define S 2048
#define DM 512
#define NH 8
#define HD 64
#define NB 2
#define BH (NB * NH)
#define MROWS (NB * S) // 4096
#define QW (S / 32)    // 64 mask words per row

typedef __bf16 bf16x8 __attribute__((ext_vector_type(8)));
typedef float f32x4 __attribute__((ext_vector_type(4)));
typedef float nf4 __attribute__((ext_vector_type(4)));  // native vec for nontemporal
typedef int ni4 __attribute__((ext_vector_type(4)));    // native vec for nontemporal

// 0.125 (1/sqrt(HD)) * log2(e): folded into bf16 Q at projection time so the
// softmax exp becomes a bare v_exp_f32 (exp2) in both S*S passes.
#define QSCALE 0.18033688011112042f

// hardware 2^x (v_exp_f32); avoids the glibc __exp2f macro collision.
__device__ __forceinline__ float hw_exp2(float x) {
  return __builtin_amdgcn_exp2f(x);
}

union FragU {
  uint4 u;
  bf16x8 v;
  unsigned short s[8];
};

__device__ __forceinline__ unsigned short f2bf(float x) {
  unsigned u = __float_as_uint(x);
  u += 0x7FFFu + ((u >> 16) & 1u); // RNE
  return (unsigned short)(u >> 16);
}

// ---------------- prep: wtrans + fp32->bf16 cvt + maskpack ------------------
// grid.x = 256 (wtrans) + 3072 (cvt) + 1024 (maskpack) = 4352
// (Z zeroing removed: Z planes are now written non-atomically, no init needed)
__global__ __launch_bounds__(256) void k_prep(
    const float* __restrict__ w0, const float* __restrict__ w1,
    const float* __restrict__ w2, const float* __restrict__ w3,
    unsigned short* __restrict__ wt,
    const float* __restrict__ q, const float* __restrict__ k, const float* __restrict__ v,
    unsigned short* __restrict__ oq, unsigned short* __restrict__ ok, unsigned short* __restrict__ ov,
    const int* __restrict__ mask, unsigned* __restrict__ mp) {
  __shared__ float tile[64][65];
  int bid = blockIdx.x;
  int tid = threadIdx.x;
  if (bid < 256) {
    // ---- weight transpose + bf16: wt[i][n][k] = W_i[k][n]
    int i = bid >> 6, rem = bid & 63;
    const float* w = (i == 0) ? w0 : (i == 1) ? w1 : (i == 2) ? w2 : w3;
    int k0 = (rem & 7) * 64, n0 = (rem >> 3) * 64;
    int tx = tid & 63, ty = tid >> 6;
    for (int r = ty; r < 64; r += 4)
      tile[r][tx] = w[(size_t)(k0 + r) * DM + n0 + tx];
    __syncthreads();
    unsigned short* o = wt + (size_t)i * DM * DM;
    for (int r = ty; r < 64; r += 4)
      o[(size_t)(n0 + r) * DM + k0 + tx] = f2bf(tile[tx][r]);
  } else if (bid < 3328) {
    // ---- activation convert (read-once: nontemporal loads, protect L2)
    int b2 = bid - 256;
    int which = b2 >> 10;
    const float* src = (which == 0) ? q : (which == 1) ? k : v;
    unsigned short* dst = (which == 0) ? oq : (which == 1) ? ok : ov;
    size_t t = (size_t)(b2 & 1023) * 256 + tid;
    const nf4* s4 = (const nf4*)src + t * 2;
    nf4 x = __builtin_nontemporal_load(s4);
    nf4 y = __builtin_nontemporal_load(s4 + 1);
    FragU f;
    f.s[0] = f2bf(x.x); f.s[1] = f2bf(x.y); f.s[2] = f2bf(x.z); f.s[3] = f2bf(x.w);
    f.s[4] = f2bf(y.x); f.s[5] = f2bf(y.y); f.s[6] = f2bf(y.z); f.s[7] = f2bf(y.w);
    *(uint4*)(dst + t * 8) = f.u;
  } else {
    // ---- mask bitpack: mp word t covers mask[t*32 .. t*32+31] (read-once: nt)
    size_t t = (size_t)(bid - 3328) * 256 + tid;
    const ni4* mb = (const ni4*)(mask + t * 32);
    unsigned bits = 0;
#pragma unroll
    for (int c = 0; c < 8; c++) {
      ni4 m = __builtin_nontemporal_load(mb + c);
      bits |= (m.x != 0 ? 1u : 0u) << (c * 4);
      bits |= (m.y != 0 ? 1u : 0u) << (c * 4 + 1);
      bits |= (m.z != 0 ? 1u : 0u) << (c * 4 + 2);
      bits |= (m.w != 0 ? 1u : 0u) << (c * 4 + 3);
    }
    mp[t] = bits;
  }
}

// ---------------- QKV projection (V fused transpose -> vvT[bh][d][s]) -------
// Q output is pre-scaled by QSCALE so logits arrive in log2-domain units.
__global__ __launch_bounds__(256) void k_proj(
    const unsigned short* __restrict__ inq, const unsigned short* __restrict__ ink,
    const unsigned short* __restrict__ inv, const unsigned short* __restrict__ wt,
    const float* __restrict__ bq, const float* __restrict__ bk, const float* __restrict__ bv,
    unsigned short* __restrict__ oq, unsigned short* __restrict__ ok,
    unsigned short* __restrict__ vvT) {
  __shared__ __align__(16) unsigned short vt[64][72]; // [d][s_local]
  int which = blockIdx.z;
  const unsigned short* in = (which == 0) ? inq : (which == 1) ? ink : inv;
  const float* bias = (which == 0) ? bq : (which == 1) ? bk : bv;
  const unsigned short* w = wt + (size_t)which * DM * DM;

  int lane = threadIdx.x & 63, wv = threadIdx.x >> 6;
  int m0 = blockIdx.x * 64 + wv * 16;
  int n0 = blockIdx.y * 64;
  int kf = (lane >> 4) * 8;
  int arow = m0 + (lane & 15);

  f32x4 acc[4] = {{0.f, 0.f, 0.f, 0.f}, {0.f, 0.f, 0.f, 0.f},
                  {0.f, 0.f, 0.f, 0.f}, {0.f, 0.f, 0.f, 0.f}};

  for (int kk0 = 0; kk0 < DM; kk0 += 32) {
    FragU af;
    af.u = *(const uint4*)(in + (size_t)arow * DM + kk0 + kf);
#pragma unroll
    for (int nt = 0; nt < 4; nt++) {
      FragU bfr;
      bfr.u = *(const uint4*)(w + (size_t)(n0 + nt * 16 + (lane & 15)) * DM + kk0 + kf);
      acc[nt] = __builtin_amdgcn_mfma_f32_16x16x32_bf16(af.v, bfr.v, acc[nt], 0, 0, 0);
    }
  }

  if (which < 2) {
    unsigned short* out = (which == 0) ? oq : ok;
    float sc = (which == 0) ? QSCALE : 1.0f;
#pragma unroll
    for (int nt = 0; nt < 4; nt++) {
#pragma unroll
      for (int r = 0; r < 4; r++) {
        int row = m0 + (lane >> 4) * 4 + r;   // b*S + s
        int col = n0 + nt * 16 + (lane & 15); // h*64 + d
        float val = (acc[nt][r] + bias[col]) * sc;
        int b = row >> 11, sIdx = row & (S - 1);
        int h = col >> 6, d = col & 63;
        out[(((size_t)(b * NH + h) * S) + sIdx) * HD + d] = f2bf(val);
      }
    }
  } else {
    // stage bias-added bf16 tile transposed in LDS, then write vvT coalesced
#pragma unroll
    for (int nt = 0; nt < 4; nt++) {
#pragma unroll
      for (int r = 0; r < 4; r++) {
        int sl = wv * 16 + (lane >> 4) * 4 + r;
        int dl = nt * 16 + (lane & 15);
        vt[dl][sl] = f2bf(acc[nt][r] + bias[n0 + dl]);
      }
    }
    __syncthreads();
    int b = (blockIdx.x * 64) >> 11;
    int s0l = (blockIdx.x * 64) & (S - 1);
    int h = n0 >> 6;
    unsigned short* op = vvT + (size_t)(b * NH + h) * HD * S;
    int d = threadIdx.x >> 2;
    int sc2 = (threadIdx.x & 3) * 16;
#pragma unroll
    for (int j = 0; j < 2; j++)
      *(uint4*)&op[(size_t)d * S + s0l + sc2 + j * 8] = *(uint4*)&vt[d][sc2 + j * 8];
  }
}

// ---------------- pass 1: Zpart[z][bh][k] = sum_q exp(logit) (masked -> 0) ---
// Round-2 grid (32,16,2) kept (verified L2-resident). NEW: the 64x64 Q tile is
// cooperatively staged in LDS once per step (was: 4 waves each loading the
// IDENTICAL global fragments -> 4x duplicated L1/L2 traffic). Double-buffered,
// one barrier per step. Z written non-atomically to per-z planes.
__global__ __launch_bounds__(256, 4) void k_softmax_z(
    const unsigned short* __restrict__ qq, const unsigned short* __restrict__ kk,
    const unsigned* __restrict__ mp, float* __restrict__ Zpart) {
  __shared__ __align__(16) unsigned short qs[2][64][72]; // [buf][q_local][d]
  int lane = threadIdx.x & 63, w = threadIdx.x >> 6;
  int bh = blockIdx.y;
  int b = bh >> 3;
  int k0 = blockIdx.x * 64 + w * 16;
  int kf = (lane >> 4) * 8;
  int qbase = blockIdx.z * (S / 2);
  int krow_b = k0 + (lane >> 4) * 4;

  const unsigned short* kbase = kk + ((size_t)bh * S + k0 + (lane & 15)) * HD + kf;
  FragU a0, a1;
  a0.u = *(const uint4*)kbase;
  a1.u = *(const uint4*)(kbase + 32);

  const unsigned short* qbaseP = qq + (size_t)bh * S * HD;
  const unsigned* mpb = mp + (size_t)b * S * QW;

  // staging indices: 4 threads per q-row, 32 B (16 ushorts) each
  int sqr = threadIdx.x >> 2;         // 0..63 q-row
  int sdc = (threadIdx.x & 3) * 16;   // 0,16,32,48 d-col

  float sum[4] = {0.f, 0.f, 0.f, 0.f};

  // prologue: stage first tile
  {
    const unsigned short* qp = qbaseP + (size_t)(qbase + sqr) * HD + sdc;
    *(uint4*)&qs[0][sqr][sdc] = *(const uint4*)qp;
    *(uint4*)&qs[0][sqr][sdc + 8] = *(const uint4*)(qp + 8);
  }
  __syncthreads();

  int buf = 0;
  for (int q0 = qbase; q0 < qbase + S / 2; q0 += 64) {
    // stage next tile into the other buffer (drained by the barrier below)
    if (q0 + 64 < qbase + S / 2) {
      const unsigned short* qp = qbaseP + (size_t)(q0 + 64 + sqr) * HD + sdc;
      *(uint4*)&qs[buf ^ 1][sqr][sdc] = *(const uint4*)qp;
      *(uint4*)&qs[buf ^ 1][sqr][sdc + 8] = *(const uint4*)(qp + 8);
    }
    uint2 mw[4];
#pragma unroll
    for (int r = 0; r < 4; r++)
      mw[r] = *(const uint2*)&mpb[(size_t)(krow_b + r) * QW + (q0 >> 5)];
#pragma unroll
    for (int nt = 0; nt < 4; nt++) {
      FragU b0, b1;
      b0.u = *(const uint4*)&qs[buf][nt * 16 + (lane & 15)][kf];
      b1.u = *(const uint4*)&qs[buf][nt * 16 + (lane & 15)][kf + 32];
      f32x4 c = {0.f, 0.f, 0.f, 0.f};
      c = __builtin_amdgcn_mfma_f32_16x16x32_bf16(a0.v, b0.v, c, 0, 0, 0);
      c = __builtin_amdgcn_mfma_f32_16x16x32_bf16(a1.v, b1.v, c, 0, 0, 0);
      unsigned bpos = (unsigned)(nt * 16 + (lane & 15)) & 31u;
#pragma unroll
      for (int r = 0; r < 4; r++) {
        unsigned word = (nt < 2) ? mw[r].x : mw[r].y;
        float e = hw_exp2(c[r]);
        sum[r] += ((word >> bpos) & 1u) ? 0.f : e;
      }
    }
    __syncthreads(); // everyone done reading buf; next-tile stage writes drained
    buf ^= 1;
  }
  float* zp = Zpart + ((size_t)blockIdx.z * BH + bh) * S;
#pragma unroll
  for (int r = 0; r < 4; r++) {
    float s = sum[r];
    s += __shfl_xor(s, 1);
    s += __shfl_xor(s, 2);
    s += __shfl_xor(s, 4);
    s += __shfl_xor(s, 8);
    if ((lane & 15) == 0)
      zp[krow_b + r] = s; // exactly one writer per element, no init needed
  }
}

// ---------------- pass 2: attn write + O = A^T V (both k-halves in-block) ----
// 8 waves: group g = w>>2 owns k-half g. Partial O reduced through LDS,
// written directly as bf16 concat — no pO round-trip, no k_reduceO.
__global__ __launch_bounds__(512, 4) void k_attn(
    const unsigned short* __restrict__ qq, const unsigned short* __restrict__ kk,
    const unsigned short* __restrict__ vvT, const unsigned* __restrict__ mp,
    const float* __restrict__ Zpart, float* __restrict__ attn_out,
    unsigned short* __restrict__ conc) {
  __shared__ __align__(16) unsigned short pT[2][2][64][72]; // [group][buf][q_local][k_local]
  int lane = threadIdx.x & 63, w = threadIdx.x >> 6;
  int g = w >> 2, w4 = w & 3;
  int bh = blockIdx.y;
  int b = bh >> 3, h = bh & 7;
  int q0 = blockIdx.x * 64;
  int kf = (lane >> 4) * 8;

  // resident Q B-frags (reused for every k-tile)
  FragU bq[4][2];
#pragma unroll
  for (int nt = 0; nt < 4; nt++) {
    const unsigned short* qp = qq + ((size_t)bh * S + q0 + nt * 16 + (lane & 15)) * HD + kf;
    bq[nt][0].u = *(const uint4*)qp;
    bq[nt][1].u = *(const uint4*)(qp + 32);
  }

  f32x4 o[4] = {{0.f, 0.f, 0.f, 0.f}, {0.f, 0.f, 0.f, 0.f},
                {0.f, 0.f, 0.f, 0.f}, {0.f, 0.f, 0.f, 0.f}};

  const unsigned short* kkb = kk + (size_t)bh * S * HD;
  const unsigned short* vb = vvT + (size_t)bh * HD * S;
  const unsigned* mpb = mp + (size_t)b * S * QW;
  float* ao = attn_out + (size_t)bh * S * S;
  const float* zb0 = Zpart + (size_t)bh * S;
  const float* zb1 = Zpart + (size_t)(BH + bh) * S;
  int q0w = q0 >> 5;
  int kbase = g * (S / 2);

  int buf = 0;
  for (int k0 = kbase; k0 < kbase + S / 2; k0 += 64) {
    int kw = k0 + w4 * 16;
    int krow_b = kw + (lane >> 4) * 4;
    const unsigned short* kp = kkb + (size_t)(kw + (lane & 15)) * HD + kf;
    FragU a0, a1;
    a0.u = *(const uint4*)kp;
    a1.u = *(const uint4*)(kp + 32);
    float iz[4];
    uint2 mw[4];
#pragma unroll
    for (int r = 0; r < 4; r++) {
      iz[r] = 1.0f / (zb0[krow_b + r] + zb1[krow_b + r]);
      mw[r] = *(const uint2*)&mpb[(size_t)(krow_b + r) * QW + q0w];
    }

#pragma unroll
    for (int nt = 0; nt < 4; nt++) {
      f32x4 c = {0.f, 0.f, 0.f, 0.f};
      c = __builtin_amdgcn_mfma_f32_16x16x32_bf16(a0.v, bq[nt][0].v, c, 0, 0, 0);
      c = __builtin_amdgcn_mfma_f32_16x16x32_bf16(a1.v, bq[nt][1].v, c, 0, 0, 0);
      int ql = nt * 16 + (lane & 15);
      int qcol = q0 + ql;
      unsigned bpos = (unsigned)ql & 31u;
#pragma unroll
      for (int r = 0; r < 4; r++) {
        int kl = w4 * 16 + (lane >> 4) * 4 + r;
        int krow = k0 + kl;
        unsigned word = (nt < 2) ? mw[r].x : mw[r].y;
        float a = ((word >> bpos) & 1u) ? 0.f : hw_exp2(c[r]) * iz[r];
        // attn is write-once, never re-read: keep it out of L2 so K/V stay hot
        __builtin_nontemporal_store(a, &ao[(size_t)krow * S + qcol]);
        pT[g][buf][ql][kl] = f2bf(a);
      }
    }
    __syncthreads();
    // waves' own lgkmcnt(0) drains before their next barrier, so reading buf here
    // is safe against the write to the same buf two iterations later.
#pragma unroll
    for (int ks = 0; ks < 2; ks++) {
      FragU af;
      af.u = *(const uint4*)(&pT[g][buf][w4 * 16 + (lane & 15)][kf + ks * 32]);
#pragma unroll
      for (int nt = 0; nt < 4; nt++) {
        FragU bfr;
        bfr.u = *(const uint4*)(vb + (size_t)(nt * 16 + (lane & 15)) * S + k0 + kf + ks * 32);
        o[nt] = __builtin_amdgcn_mfma_f32_16x16x32_bf16(af.v, bfr.v, o[nt], 0, 0, 0);
      }
    }
    buf ^= 1;
  }

  // ---- cross-group O reduction through LDS (aliased over pT), write conc ----
  __syncthreads(); // all PV reads of pT done before we clobber it
  float* oacc = (float*)&pT[0][0][0][0]; // 64 rows x 65 floats = 16.6 KB
  int qr = w4 * 16 + (lane >> 4) * 4;
  if (g == 1) {
#pragma unroll
    for (int nt = 0; nt < 4; nt++)
#pragma unroll
      for (int r = 0; r < 4; r++)
        oacc[(qr + r) * 65 + nt * 16 + (lane & 15)] = o[nt][r];
  }
  __syncthreads();
  if (g == 0) {
#pragma unroll
    for (int nt = 0; nt < 4; nt++) {
#pragma unroll
      for (int r = 0; r < 4; r++) {
        int qg = q0 + qr + r;
        int col = h * 64 + nt * 16 + (lane & 15);
        float s = o[nt][r] + oacc[(qr + r) * 65 + nt * 16 + (lane & 15)];
        conc[((size_t)(b * S + qg)) * DM + col] = f2bf(s);
      }
    }
  }
}

// ---------------- out projection: out = concat @ Wo + bo ---------------------
__global__ __launch_bounds__(256) void k_outproj(
    const unsigned short* __restrict__ concat, const unsigned short* __restrict__ wt,
    const float* __restrict__ bias, float* __restrict__ out) {
  const unsigned short* w = wt + (size_t)3 * DM * DM;
  int lane = threadIdx.x & 63, wv = threadIdx.x >> 6;
  int m0 = blockIdx.x * 64 + wv * 16;
  int n0 = blockIdx.y * 64;
  int kf = (lane >> 4) * 8;

  f32x4 acc[4] = {{0.f, 0.f, 0.f, 0.f}, {0.f, 0.f, 0.f, 0.f},
                  {0.f, 0.f, 0.f, 0.f}, {0.f, 0.f, 0.f, 0.f}};

  for (int kk0 = 0; kk0 < DM; kk0 += 32) {
    FragU af;
    af.u = *(const uint4*)(concat + (size_t)(m0 + (lane & 15)) * DM + kk0 + kf);
#pragma unroll
    for (int nt = 0; nt < 4; nt++) {
      FragU bfr;
      bfr.u = *(const uint4*)(w + (size_t)(n0 + nt * 16 + (lane & 15)) * DM + kk0 + kf);
      acc[nt] = __builtin_amdgcn_mfma_f32_16x16x32_bf16(af.v, bfr.v, acc[nt], 0, 0, 0);
    }
  }
#pragma unroll
  for (int nt = 0; nt < 4; nt++) {
#pragma unroll
    for (int r = 0; r < 4; r++) {
      int row = m0 + (lane >> 4) * 4 + r;
      int col = n0 + nt * 16 + (lane & 15);
      out[(size_t)row * DM + col] = acc[nt][r] + bias[col];
    }
  }
}

extern "C" void kernel_launch(void* const* d_in, const int* in_sizes, int n_in,
                              void* d_out, int out_size, void* d_ws, size_t ws_size,
                              hipStream_t stream) {
  (void)in_sizes; (void)n_in; (void)out_size; (void)ws_size;
  const float* v    = (const float*)d_in[0];
  const float* q    = (const float*)d_in[1];
  const float* k    = (const float*)d_in[2];
  const int*   mask = (const int*)d_in[3];
  const float* wq_w = (const float*)d_in[4];
  const float* wq_b = (const float*)d_in[5];
  const float* wk_w = (const float*)d_in[6];
  const float* wk_b = (const float*)d_in[7];
  const float* wv_w = (const float*)d_in[8];
  const float* wv_b = (const float*)d_in[9];
  const float* wo_w = (const float*)d_in[10];
  const float* wo_b = (const float*)d_in[11];

  char* ws = (char*)d_ws;
  size_t off = 0;
  auto alloc = [&](size_t bytes) {
    char* p = ws + off;
    off += (bytes + 255) & ~(size_t)255;
    return p;
  };
  unsigned short* wt   = (unsigned short*)alloc((size_t)4 * DM * DM * 2);   // 2 MB
  unsigned short* qbf  = (unsigned short*)alloc((size_t)MROWS * DM * 2);    // 4 MB
  unsigned short* kbf  = (unsigned short*)alloc((size_t)MROWS * DM * 2);    // 4 MB
  unsigned short* vbf  = (unsigned short*)alloc((size_t)MROWS * DM * 2);    // 4 MB
  unsigned short* qq   = (unsigned short*)alloc((size_t)BH * S * HD * 2);   // 4 MB
  unsigned short* kk2  = (unsigned short*)alloc((size_t)BH * S * HD * 2);   // 4 MB
  unsigned short* vvT  = (unsigned short*)alloc((size_t)BH * S * HD * 2);   // 4 MB
  unsigned*       mp   = (unsigned*)alloc((size_t)NB * S * QW * 4);         // 1 MB
  float*          Zs   = (float*)alloc((size_t)2 * BH * S * 4);             // 256 KB (2 planes)
  unsigned short* conc = (unsigned short*)alloc((size_t)MROWS * DM * 2);    // 4 MB

  float* out_final = (float*)d_out;
  float* out_attn  = (float*)d_out + (size_t)MROWS * DM;

  k_prep<<<dim3(4352), 256, 0, stream>>>(wq_w, wk_w, wv_w, wo_w, wt,
                                          q, k, v, qbf, kbf, vbf,
                                          mask, mp);
  k_proj<<<dim3(64, 8, 3), 256, 0, stream>>>(qbf, kbf, vbf, wt, wq_b, wk_b, wv_b,
                                              qq, kk2, vvT);
  k_softmax_z<<<dim3(32, 16, 2), 256, 0, stream>>>(qq, kk2, mp, Zs);
  k_attn<<<dim3(32, 16), 512, 0, stream>>>(qq, kk2, vvT, mp, Zs, out_attn, conc);
  k_outproj<<<dim3(64, 8), 256, 0, stream>>>(conc, wt, wo_b, out_final);
}